// Round 3
// baseline (408.838 us; speedup 1.0000x reference)
//
#include <hip/hip_runtime.h>
#include <hip/hip_bf16.h>

typedef __attribute__((ext_vector_type(8))) short bf16x8;
typedef __attribute__((ext_vector_type(4))) float f32x4;

#define T_SEQ   512
#define B_BATCH 128
#define H_DIM   64
#define MB      64               // rows (t*B+b) per block
#define A1S     72               // bf16 per row of A split-plane (64 + 8 pad; 144B = 9x16B)
#define ZQ_STRIDE 193            // f32 per row of z quarter-tile (192 + 1 pad)
#define A2S       72             // bf16 per row of layer-2 A split-plane (64 + 8 pad; 144B)
#define LASTROW ((T_SEQ - 1) * B_BATCH)   // 65408

// ws layout (shorts): W0 gate-rows (192x512) planes h/m/l, then W1 (192x64) h/m/l
#define W0H 0
#define W0M 98304
#define W0L 196608
#define W1H 294912
#define W1M 307200
#define W1L 319488
// total 331776 shorts = 663552 bytes of d_ws

// truncation 3-way split: f = h + m + l + r, |r| <= ~2^-24 |f|; subtractions exact
__device__ __forceinline__ void tsplit(float f, unsigned& h, unsigned& m, unsigned& l) {
    unsigned uf = __builtin_bit_cast(unsigned, f);
    h = uf >> 16;
    float hf = __builtin_bit_cast(float, uf & 0xFFFF0000u);
    float r1 = f - hf;
    unsigned u1 = __builtin_bit_cast(unsigned, r1);
    m = u1 >> 16;
    float mf = __builtin_bit_cast(float, u1 & 0xFFFF0000u);
    float r2 = r1 - mf;
    l = __builtin_bit_cast(unsigned, r2) >> 16;
}

// split two floats, pack into one dword per plane (elem0 low, elem1 high)
__device__ __forceinline__ void tsplit2(float a, float b,
                                        unsigned& ph, unsigned& pm, unsigned& pl) {
    unsigned ha, ma, la, hb, mb, lb;
    tsplit(a, ha, ma, la);
    tsplit(b, hb, mb, lb);
    ph = ha | (hb << 16);
    pm = ma | (mb << 16);
    pl = la | (lb << 16);
}

// split 16 floats (4 float4) into 3 planes at shorts-offset ao (row-contiguous 16 cols)
__device__ __forceinline__ void split16(const float4 f[4],
                                        short* __restrict__ ah, short* __restrict__ am,
                                        short* __restrict__ al, int ao) {
    uint4 Ph, Pm, Pl;
    tsplit2(f[0].x, f[0].y, Ph.x, Pm.x, Pl.x);
    tsplit2(f[0].z, f[0].w, Ph.y, Pm.y, Pl.y);
    tsplit2(f[1].x, f[1].y, Ph.z, Pm.z, Pl.z);
    tsplit2(f[1].z, f[1].w, Ph.w, Pm.w, Pl.w);
    *(uint4*)(ah + ao) = Ph;
    *(uint4*)(am + ao) = Pm;
    *(uint4*)(al + ao) = Pl;
    tsplit2(f[2].x, f[2].y, Ph.x, Pm.x, Pl.x);
    tsplit2(f[2].z, f[2].w, Ph.y, Pm.y, Pl.y);
    tsplit2(f[3].x, f[3].y, Ph.z, Pm.z, Pl.z);
    tsplit2(f[3].z, f[3].w, Ph.w, Pm.w, Pl.w);
    *(uint4*)(ah + ao + 8) = Ph;
    *(uint4*)(am + ao + 8) = Pm;
    *(uint4*)(al + ao + 8) = Pl;
}

// 6-product accumulate: (h1+m1+l1)(h2+m2+l2), dropping ml, lm, ll (~2^-24 |ab|)
__device__ __forceinline__ f32x4 mfma6(bf16x8 ah, bf16x8 am, bf16x8 al,
                                       bf16x8 bh, bf16x8 bm, bf16x8 bl, f32x4 c) {
    c = __builtin_amdgcn_mfma_f32_16x16x32_bf16(ah, bh, c, 0, 0, 0);
    c = __builtin_amdgcn_mfma_f32_16x16x32_bf16(ah, bm, c, 0, 0, 0);
    c = __builtin_amdgcn_mfma_f32_16x16x32_bf16(am, bh, c, 0, 0, 0);
    c = __builtin_amdgcn_mfma_f32_16x16x32_bf16(ah, bl, c, 0, 0, 0);
    c = __builtin_amdgcn_mfma_f32_16x16x32_bf16(al, bh, c, 0, 0, 0);
    c = __builtin_amdgcn_mfma_f32_16x16x32_bf16(am, bm, c, 0, 0, 0);
    return c;
}

// branch-free Cody-Waite cos, ~1 ulp for |x| <~ 30 (args here are |z+bt| <~ 9).
__device__ __forceinline__ float fast_cos(float x) {
    float n = rintf(x * 0.6366197723675814f);          // 2/pi
    int   m = (int)n;
    float r = __builtin_fmaf(n, -1.5707962512969971e+00f, x);
    r = __builtin_fmaf(n, -7.5497894158615964e-08f, r);
    r = __builtin_fmaf(n, -5.3903025299577647e-15f, r);
    float r2 = r * r;
    float ps = __builtin_fmaf(r2, 2.7557314297e-06f, -1.9841270114e-04f);
    ps = __builtin_fmaf(r2, ps, 8.3333337680e-03f);
    ps = __builtin_fmaf(r2, ps, -1.6666667163e-01f);
    float s = __builtin_fmaf(r * r2, ps, r);
    float pc = __builtin_fmaf(r2, 2.4801587642e-05f, -1.3888889225e-03f);
    pc = __builtin_fmaf(r2, pc, 4.1666667908e-02f);
    pc = __builtin_fmaf(r2, pc, -0.5f);
    float c = __builtin_fmaf(r2, pc, 1.0f);
    float v = (m & 1) ? s : c;
    unsigned sign = (unsigned)((m + 1) & 2) << 30;     // 0 or 0x80000000
    return __builtin_bit_cast(float, __builtin_bit_cast(unsigned, v) ^ sign);
}

// sigmoid via native v_exp (~2 ulp) + hw rcp with one Newton step
__device__ __forceinline__ float fast_sigmoid(float x) {
    float e = __expf(-x);
    float d = 1.0f + e;
    float r = __builtin_amdgcn_rcpf(d);
    return r * (2.0f - d * r);
}

// tanh for x >= 0 (args here are in (0,1)): (e^2x - 1)/(e^2x + 1); abs err ~2e-7
__device__ __forceinline__ float fast_tanh_pos(float x) {
    float t = __expf(2.0f * x);
    float d = t + 1.0f;
    float r = __builtin_amdgcn_rcpf(d);
    r = r * (2.0f - d * r);
    return (t - 1.0f) * r;
}

// ---------- kernel 1: pre-split weights into d_ws (runs every launch; ~5 us) ----------
__global__ __launch_bounds__(256) void presplit_w(const float* __restrict__ W0,
                                                  const float* __restrict__ W1,
                                                  short* __restrict__ ws) {
    int i = blockIdx.x * 256 + threadIdx.x;
    if (i < 98304) {                      // W0 gates 1..3: flat rows 64..255, stride 576
        int r = i >> 9, k = i & 511;
        unsigned h, m, l;
        tsplit(W0[(r + 64) * 576 + k], h, m, l);
        ws[W0H + i] = (short)h;
        ws[W0M + i] = (short)m;
        ws[W0L + i] = (short)l;
    } else if (i < 110592) {              // W1 gates 1..3: rows 64..255, stride 128, k<64
        int j = i - 98304;
        int r = j >> 6, k = j & 63;
        unsigned h, m, l;
        tsplit(W1[(r + 64) * 128 + k], h, m, l);
        ws[W1H + j] = (short)h;
        ws[W1M + j] = (short)m;
        ws[W1L + j] = (short)l;
    }
}

// ---------- kernel 2: fused QLSTM ----------
// LDS layout (total 40000 B -> 4 blocks/CU even at 1KiB granularity):
//   [0, 12352)       zs_q [16][193] f32 (one 16-row quarter of the z tile)
//   [12352, 40000)   A2 split-planes [64][72] bf16 x3 (27648)
//   [0, 27648)       A1 split-planes [64][72] bf16 x3 -- GEMM1 only, dead before
//                    zs_q / A2 are first written (aliases both)
// bias+theta no longer staged in LDS: cumprod reads b/th from global (L2-hot, 1KB)
__global__ __launch_bounds__(256, 4) void qlstm_fused(
    const float* __restrict__ x,
    const float* __restrict__ b0,
    const float* __restrict__ th0,
    const float* __restrict__ g0,
    const float* __restrict__ be0,
    const float* __restrict__ b1,
    const float* __restrict__ th1,
    const float* __restrict__ g1,
    const float* __restrict__ be1,
    const short* __restrict__ wsp,      // pre-split weight planes
    float* __restrict__ out)
{
    __shared__ __align__(16) char lds[40000];
    short* ah = (short*)lds;                      // [64][72]  (GEMM1 staging)
    short* am = ah + 64 * A1S;
    short* al = am + 64 * A1S;
    float* zs  = (float*)lds;                     // [16][193] quarter z tile
    short* a2h = (short*)(lds + 12352);           // [64][72]  layer-2 A planes
    short* a2m = a2h + 64 * A2S;
    short* a2l = a2m + 64 * A2S;

    const int tid = threadIdx.x;
    const long rowbase = (long)blockIdx.x * MB;

    float* out0 = out;                                      // h1      [T*B][64]
    float* out1 = out + (long)T_SEQ * B_BATCH * H_DIM;      // h0[-1]  [128][64]
    float* out2 = out1 + B_BATCH * H_DIM;                   // c0[-1]
    float* out3 = out2 + B_BATCH * H_DIM;                   // h1[-1]
    float* out4 = out3 + B_BATCH * H_DIM;                   // c1[-1]

    const int lane = tid & 63;
    const int wave = tid >> 6;
    const int ln   = lane & 15;   // MFMA m/n lane index
    const int quad = lane >> 4;   // MFMA k-group / row-group
    const int cw   = wave * 48;   // this wave's N-column base (192 cols / 4 waves)

    // B plane row offsets (in shorts) for this wave's 3 column-tiles
    int brow0[3], brow1[3];
    for (int nt = 0; nt < 3; ++nt) {
        int gc = cw + nt * 16 + ln;
        brow0[nt] = gc * 512;
        brow1[nt] = gc * 64;
    }

    // staging geometry: each thread owns 16 contiguous cols of one row per K=64 chunk
    const int sr = tid >> 2;            // row 0..63
    const int sc = (tid & 3) << 4;      // col base 0,16,32,48
    const float* xrow = x + (rowbase + sr) * 512 + sc;
    const int sao = sr * A1S + sc;

    // ------- GEMM1: z0[64][192] = x[64][512] . W0g^T, K chunks of 64, async-staged
    f32x4 acc[4][3];
    #pragma unroll
    for (int mt = 0; mt < 4; ++mt)
        #pragma unroll
        for (int nt = 0; nt < 3; ++nt)
            acc[mt][nt] = (f32x4){0.f, 0.f, 0.f, 0.f};

    {   // prologue: stage chunk 0
        float4 f[4];
        #pragma unroll
        for (int u = 0; u < 4; ++u) f[u] = *(const float4*)(xrow + u * 4);
        split16(f, ah, am, al, sao);
    }
    __syncthreads();

    for (int kc = 0; kc < 512; kc += 64) {
        // T14 async-stage: issue next chunk's global loads BEFORE compute;
        // latency hides under the MFMA phase; split+write after the barrier.
        float4 nf[4];
        const bool more = (kc + 64) < 512;
        if (more) {
            #pragma unroll
            for (int u = 0; u < 4; ++u)
                nf[u] = *(const float4*)(xrow + kc + 64 + u * 4);
        }
        #pragma unroll
        for (int k0 = 0; k0 < 64; k0 += 32) {
            int ka = k0 + quad * 8;
            bf16x8 Ah[4], Am[4], Al[4];
            #pragma unroll
            for (int mt = 0; mt < 4; ++mt) {
                int ao = (mt * 16 + ln) * A1S + ka;
                Ah[mt] = *(const bf16x8*)(ah + ao);
                Am[mt] = *(const bf16x8*)(am + ao);
                Al[mt] = *(const bf16x8*)(al + ao);
            }
            #pragma unroll
            for (int nt = 0; nt < 3; ++nt) {
                int bo = brow0[nt] + kc + ka;
                bf16x8 Bh = *(const bf16x8*)(wsp + W0H + bo);
                bf16x8 Bm = *(const bf16x8*)(wsp + W0M + bo);
                bf16x8 Bl = *(const bf16x8*)(wsp + W0L + bo);
                #pragma unroll
                for (int mt = 0; mt < 4; ++mt)
                    acc[mt][nt] = mfma6(Ah[mt], Am[mt], Al[mt], Bh, Bm, Bl, acc[mt][nt]);
            }
        }
        __syncthreads();   // plane reads done before overwrite / quarter processing
        if (more) {
            split16(nf, ah, am, al, sao);
            __syncthreads();
        }
    }

    // ------- layer 0: process in 4 row-quarters of 16 (quarter qd == acc[mt=qd])
    // per quarter: epilogue -> zs_q, cumprod (48 thr), gates+LN (64 thr) -> A2 planes
    #pragma unroll
    for (int qd = 0; qd < 4; ++qd) {
        // qd=0: A1-plane reads all done (barrier above); qd>0: prev quarter's zs
        // reads finished before its A2 write, but epilogue overwrite needs a fence:
        if (qd > 0) __syncthreads();
        // epilogue: D[m][n]: col = lane&15, row = quad*4 + reg  [measured m89/m91]
        #pragma unroll
        for (int nt = 0; nt < 3; ++nt)
            #pragma unroll
            for (int i = 0; i < 4; ++i)
                zs[(quad * 4 + i) * ZQ_STRIDE + cw + nt * 16 + ln] = acc[qd][nt][i];
        __syncthreads();

        // cumprod(cos(z + b + th)): 48 chains (16 rows x 3 gates), wave 0 only
        if (tid < 48) {
            int gi = tid >> 4;
            int r  = tid & 15;
            float* zrow = zs + r * ZQ_STRIDE + gi * 64;
            const float* bg = b0 + 64 + gi * 64;
            const float* tg = th0 + 64 + gi * 64;
            float p = 1.0f;
            for (int n = 0; n < 64; ++n) {
                p *= fast_cos(zrow[n] + bg[n] + tg[n]);
                zrow[n] = p;
            }
        }
        __syncthreads();

        // gates + two-pass LayerNorm -> registers -> split into A2 planes
        if (tid < 64) {
            int r = tid >> 2;            // row 0..15 within quarter
            int j = tid & 3;             // 16-element chunk
            int rloc = qd * 16 + r;      // row within block tile
            long tbrow = rowbase + rloc;
            bool lastt = (tbrow >= LASTROW);
            int bidx = (int)(tbrow - LASTROW);
            const float* zr = zs + r * ZQ_STRIDE;
            float h[16];
            float s = 0.f;
            #pragma unroll
            for (int i = 0; i < 16; ++i) {
                int n = j * 16 + i;
                float q1 = zr[n];            // gate 1 (input)
                float q2 = zr[64 + n];       // gate 2 (update)
                float q3 = zr[128 + n];      // gate 3 (output)
                float ig = fast_sigmoid(q1);
                float gg = fast_tanh_pos(fast_sigmoid(q2));
                float og = fast_sigmoid(q3);
                float c  = ig * gg;
                float hv = og * fast_tanh_pos(c);
                h[i] = hv;
                s += hv;
                if (lastt) out2[bidx * 64 + n] = c;
            }
            s += __shfl_xor(s, 1);  s += __shfl_xor(s, 2);
            float mu = s * (1.0f / 64.0f);
            float s2 = 0.f;
            #pragma unroll
            for (int i = 0; i < 16; ++i) {           // two-pass: matches mean((h-mu)^2)
                float d = h[i] - mu;
                s2 += d * d;
            }
            s2 += __shfl_xor(s2, 1); s2 += __shfl_xor(s2, 2);
            float var = s2 * (1.0f / 64.0f);
            float rs  = rsqrtf(var + 1e-5f);
            float hl[16];
            #pragma unroll
            for (int i = 0; i < 16; ++i) {
                int n = j * 16 + i;
                hl[i] = (h[i] - mu) * rs * g0[n] + be0[n];
                if (lastt) out1[bidx * 64 + n] = hl[i];
            }
            // split ONCE into layer-2 A planes (A2 region disjoint from zs_q)
            int ab = rloc * A2S + j * 16;
            uint4 Ph, Pm, Pl;
            tsplit2(hl[0], hl[1], Ph.x, Pm.x, Pl.x);
            tsplit2(hl[2], hl[3], Ph.y, Pm.y, Pl.y);
            tsplit2(hl[4], hl[5], Ph.z, Pm.z, Pl.z);
            tsplit2(hl[6], hl[7], Ph.w, Pm.w, Pl.w);
            *(uint4*)(a2h + ab) = Ph;
            *(uint4*)(a2m + ab) = Pm;
            *(uint4*)(a2l + ab) = Pl;
            tsplit2(hl[8],  hl[9],  Ph.x, Pm.x, Pl.x);
            tsplit2(hl[10], hl[11], Ph.y, Pm.y, Pl.y);
            tsplit2(hl[12], hl[13], Ph.z, Pm.z, Pl.z);
            tsplit2(hl[14], hl[15], Ph.w, Pm.w, Pl.w);
            *(uint4*)(a2h + ab + 8) = Ph;
            *(uint4*)(a2m + ab + 8) = Pm;
            *(uint4*)(a2l + ab + 8) = Pl;
        }
    }
    __syncthreads();   // A2 planes complete before GEMM2

    // ------- GEMM2: z1[64][192] = h0[64][64] . W1g^T, pre-split A2 planes, K=64
    f32x4 acc2[4][3];
    #pragma unroll
    for (int mt = 0; mt < 4; ++mt)
        #pragma unroll
        for (int nt = 0; nt < 3; ++nt)
            acc2[mt][nt] = (f32x4){0.f, 0.f, 0.f, 0.f};
    #pragma unroll
    for (int k0 = 0; k0 < 64; k0 += 32) {
        int ka = k0 + quad * 8;
        bf16x8 Ah[4], Am[4], Al[4];
        #pragma unroll
        for (int mt = 0; mt < 4; ++mt) {
            int ao = (mt * 16 + ln) * A2S + ka;
            Ah[mt] = *(const bf16x8*)(a2h + ao);
            Am[mt] = *(const bf16x8*)(a2m + ao);
            Al[mt] = *(const bf16x8*)(a2l + ao);
        }
        #pragma unroll
        for (int nt = 0; nt < 3; ++nt) {
            int bo = brow1[nt] + ka;
            bf16x8 Bh = *(const bf16x8*)(wsp + W1H + bo);
            bf16x8 Bm = *(const bf16x8*)(wsp + W1M + bo);
            bf16x8 Bl = *(const bf16x8*)(wsp + W1L + bo);
            #pragma unroll
            for (int mt = 0; mt < 4; ++mt)
                acc2[mt][nt] = mfma6(Ah[mt], Am[mt], Al[mt], Bh, Bm, Bl, acc2[mt][nt]);
        }
    }

    // ------- layer 1: same 4-quarter processing; gates write global directly
    #pragma unroll
    for (int qd = 0; qd < 4; ++qd) {
        __syncthreads();   // qd=0: zs_q last read in L0 q3 (fenced); also uniform
        #pragma unroll
        for (int nt = 0; nt < 3; ++nt)
            #pragma unroll
            for (int i = 0; i < 4; ++i)
                zs[(quad * 4 + i) * ZQ_STRIDE + cw + nt * 16 + ln] = acc2[qd][nt][i];
        __syncthreads();

        if (tid < 48) {
            int gi = tid >> 4;
            int r  = tid & 15;
            float* zrow = zs + r * ZQ_STRIDE + gi * 64;
            const float* bg = b1 + 64 + gi * 64;
            const float* tg = th1 + 64 + gi * 64;
            float p = 1.0f;
            for (int n = 0; n < 64; ++n) {
                p *= fast_cos(zrow[n] + bg[n] + tg[n]);
                zrow[n] = p;
            }
        }
        __syncthreads();

        if (tid < 64) {
            int r = tid >> 2;
            int j = tid & 3;
            long tbrow = rowbase + qd * 16 + r;
            bool lastt = (tbrow >= LASTROW);
            int bidx = (int)(tbrow - LASTROW);
            const float* zr = zs + r * ZQ_STRIDE;
            float h[16];
            float s = 0.f;
            #pragma unroll
            for (int i = 0; i < 16; ++i) {
                int n = j * 16 + i;
                float q1 = zr[n];
                float q2 = zr[64 + n];
                float q3 = zr[128 + n];
                float ig = fast_sigmoid(q1);
                float gg = fast_tanh_pos(fast_sigmoid(q2));
                float og = fast_sigmoid(q3);
                float c  = ig * gg;
                float hv = og * fast_tanh_pos(c);
                h[i] = hv;
                s += hv;
                if (lastt) out4[bidx * 64 + n] = c;
            }
            s += __shfl_xor(s, 1);  s += __shfl_xor(s, 2);
            float mu = s * (1.0f / 64.0f);
            float s2 = 0.f;
            #pragma unroll
            for (int i = 0; i < 16; ++i) {
                float d = h[i] - mu;
                s2 += d * d;
            }
            s2 += __shfl_xor(s2, 1); s2 += __shfl_xor(s2, 2);
            float var = s2 * (1.0f / 64.0f);
            float rs  = rsqrtf(var + 1e-5f);
            float o4[16];
            #pragma unroll
            for (int i = 0; i < 16; ++i)
                o4[i] = (h[i] - mu) * rs * g1[j * 16 + i] + be1[j * 16 + i];
            float* dst = out0 + tbrow * 64 + j * 16;
            #pragma unroll
            for (int i4 = 0; i4 < 4; ++i4)
                *(float4*)(dst + i4 * 4) = *(float4*)(o4 + i4 * 4);
            if (lastt) {
                float* dst3 = out3 + (long)bidx * 64 + j * 16;
                #pragma unroll
                for (int i4 = 0; i4 < 4; ++i4)
                    *(float4*)(dst3 + i4 * 4) = *(float4*)(o4 + i4 * 4);
            }
        }
    }
}

extern "C" void kernel_launch(void* const* d_in, const int* in_sizes, int n_in,
                              void* d_out, int out_size, void* d_ws, size_t ws_size,
                              hipStream_t stream) {
    const float* x   = (const float*)d_in[0];
    const float* W0  = (const float*)d_in[1];
    const float* b0  = (const float*)d_in[2];
    const float* th0 = (const float*)d_in[3];
    const float* g0  = (const float*)d_in[4];
    const float* be0 = (const float*)d_in[5];
    const float* W1  = (const float*)d_in[6];
    const float* b1  = (const float*)d_in[7];
    const float* th1 = (const float*)d_in[8];
    const float* g1  = (const float*)d_in[9];
    const float* be1 = (const float*)d_in[10];
    short* wsp = (short*)d_ws;     // needs 663552 B

    presplit_w<<<dim3(432), dim3(256), 0, stream>>>(W0, W1, wsp);
    qlstm_fused<<<dim3(1024), dim3(256), 0, stream>>>(
        x, b0, th0, g0, be0, b1, th1, g1, be1, wsp, (float*)d_out);
}

// Round 4
// 408.525 us; speedup vs baseline: 1.0008x; 1.0008x over previous
//
#include <hip/hip_runtime.h>
#include <hip/hip_bf16.h>

typedef __attribute__((ext_vector_type(8))) short bf16x8;
typedef __attribute__((ext_vector_type(4))) float f32x4;

#define T_SEQ   512
#define B_BATCH 128
#define H_DIM   64
#define MB      32               // rows (t*B+b) per block
#define A1S     72               // bf16 per row of A split-plane (64 + 8 pad; 144B = 9x16B)
#define ZQ_STRIDE 193            // f32 per row of z chunk tile (192 + 1 pad)
#define A2S       72             // bf16 per row of layer-2 A split-plane
#define LASTROW ((T_SEQ - 1) * B_BATCH)   // 65408

// ws layout (shorts): W0 gate-rows (192x512) planes h/m/l, then W1 (192x64) h/m/l
#define W0H 0
#define W0M 98304
#define W0L 196608
#define W1H 294912
#define W1M 307200
#define W1L 319488
// total 331776 shorts = 663552 bytes of d_ws

// truncation 3-way split: f = h + m + l + r, |r| <= ~2^-24 |f|; subtractions exact
__device__ __forceinline__ void tsplit(float f, unsigned& h, unsigned& m, unsigned& l) {
    unsigned uf = __builtin_bit_cast(unsigned, f);
    h = uf >> 16;
    float hf = __builtin_bit_cast(float, uf & 0xFFFF0000u);
    float r1 = f - hf;
    unsigned u1 = __builtin_bit_cast(unsigned, r1);
    m = u1 >> 16;
    float mf = __builtin_bit_cast(float, u1 & 0xFFFF0000u);
    float r2 = r1 - mf;
    l = __builtin_bit_cast(unsigned, r2) >> 16;
}

// split two floats, pack into one dword per plane (elem0 low, elem1 high)
__device__ __forceinline__ void tsplit2(float a, float b,
                                        unsigned& ph, unsigned& pm, unsigned& pl) {
    unsigned ha, ma, la, hb, mb, lb;
    tsplit(a, ha, ma, la);
    tsplit(b, hb, mb, lb);
    ph = ha | (hb << 16);
    pm = ma | (mb << 16);
    pl = la | (lb << 16);
}

// split 8 floats (2 float4) into 3 planes: one 16B store per plane
__device__ __forceinline__ void split8(const float4 f0, const float4 f1,
                                       short* __restrict__ ah, short* __restrict__ am,
                                       short* __restrict__ al, int ao) {
    uint4 Ph, Pm, Pl;
    tsplit2(f0.x, f0.y, Ph.x, Pm.x, Pl.x);
    tsplit2(f0.z, f0.w, Ph.y, Pm.y, Pl.y);
    tsplit2(f1.x, f1.y, Ph.z, Pm.z, Pl.z);
    tsplit2(f1.z, f1.w, Ph.w, Pm.w, Pl.w);
    *(uint4*)(ah + ao) = Ph;
    *(uint4*)(am + ao) = Pm;
    *(uint4*)(al + ao) = Pl;
}

// 6-product accumulate: (h1+m1+l1)(h2+m2+l2), dropping ml, lm, ll (~2^-24 |ab|)
__device__ __forceinline__ f32x4 mfma6(bf16x8 ah, bf16x8 am, bf16x8 al,
                                       bf16x8 bh, bf16x8 bm, bf16x8 bl, f32x4 c) {
    c = __builtin_amdgcn_mfma_f32_16x16x32_bf16(ah, bh, c, 0, 0, 0);
    c = __builtin_amdgcn_mfma_f32_16x16x32_bf16(ah, bm, c, 0, 0, 0);
    c = __builtin_amdgcn_mfma_f32_16x16x32_bf16(am, bh, c, 0, 0, 0);
    c = __builtin_amdgcn_mfma_f32_16x16x32_bf16(ah, bl, c, 0, 0, 0);
    c = __builtin_amdgcn_mfma_f32_16x16x32_bf16(al, bh, c, 0, 0, 0);
    c = __builtin_amdgcn_mfma_f32_16x16x32_bf16(am, bm, c, 0, 0, 0);
    return c;
}

// branch-free Cody-Waite cos, ~1 ulp for |x| <~ 30 (args here are |z+bt| <~ 9).
__device__ __forceinline__ float fast_cos(float x) {
    float n = rintf(x * 0.6366197723675814f);          // 2/pi
    int   m = (int)n;
    float r = __builtin_fmaf(n, -1.5707962512969971e+00f, x);
    r = __builtin_fmaf(n, -7.5497894158615964e-08f, r);
    r = __builtin_fmaf(n, -5.3903025299577647e-15f, r);
    float r2 = r * r;
    float ps = __builtin_fmaf(r2, 2.7557314297e-06f, -1.9841270114e-04f);
    ps = __builtin_fmaf(r2, ps, 8.3333337680e-03f);
    ps = __builtin_fmaf(r2, ps, -1.6666667163e-01f);
    float s = __builtin_fmaf(r * r2, ps, r);
    float pc = __builtin_fmaf(r2, 2.4801587642e-05f, -1.3888889225e-03f);
    pc = __builtin_fmaf(r2, pc, 4.1666667908e-02f);
    pc = __builtin_fmaf(r2, pc, -0.5f);
    float c = __builtin_fmaf(r2, pc, 1.0f);
    float v = (m & 1) ? s : c;
    unsigned sign = (unsigned)((m + 1) & 2) << 30;     // 0 or 0x80000000
    return __builtin_bit_cast(float, __builtin_bit_cast(unsigned, v) ^ sign);
}

// sigmoid via native v_exp (~2 ulp) + hw rcp with one Newton step
__device__ __forceinline__ float fast_sigmoid(float x) {
    float e = __expf(-x);
    float d = 1.0f + e;
    float r = __builtin_amdgcn_rcpf(d);
    return r * (2.0f - d * r);
}

// tanh for x >= 0 (args here are in (0,1)): (e^2x - 1)/(e^2x + 1); abs err ~2e-7
__device__ __forceinline__ float fast_tanh_pos(float x) {
    float t = __expf(2.0f * x);
    float d = t + 1.0f;
    float r = __builtin_amdgcn_rcpf(d);
    r = r * (2.0f - d * r);
    return (t - 1.0f) * r;
}

// ---------- kernel 1: pre-split weights into d_ws (runs every launch; ~5 us) ----------
__global__ __launch_bounds__(256) void presplit_w(const float* __restrict__ W0,
                                                  const float* __restrict__ W1,
                                                  short* __restrict__ ws) {
    int i = blockIdx.x * 256 + threadIdx.x;
    if (i < 98304) {                      // W0 gates 1..3: flat rows 64..255, stride 576
        int r = i >> 9, k = i & 511;
        unsigned h, m, l;
        tsplit(W0[(r + 64) * 576 + k], h, m, l);
        ws[W0H + i] = (short)h;
        ws[W0M + i] = (short)m;
        ws[W0L + i] = (short)l;
    } else if (i < 110592) {              // W1 gates 1..3: rows 64..255, stride 128, k<64
        int j = i - 98304;
        int r = j >> 6, k = j & 63;
        unsigned h, m, l;
        tsplit(W1[(r + 64) * 128 + k], h, m, l);
        ws[W1H + j] = (short)h;
        ws[W1M + j] = (short)m;
        ws[W1L + j] = (short)l;
    }
}

// ---------- kernel 2: fused QLSTM (MB=32 rows/block, grid 2048) ----------
// LDS layout (total 27648 B -> LDS-limit 5 blocks/CU; thread-limit 8):
//   [0, 13824)       A1 split-planes ah/am/al [32][72] bf16 (3 x 4608) -- GEMM1 only
//   [0, 12352)       zs_q [16][193] f32 (one 16-row chunk of z; aliases A1)
//   [13824, 27648)   A2 split-planes [32][72] bf16 x3 (13824)
// bias+theta read from global (L1/L2-hot, 1KB) -- no LDS staging
__global__ __launch_bounds__(256, 4) void qlstm_fused(
    const float* __restrict__ x,
    const float* __restrict__ b0,
    const float* __restrict__ th0,
    const float* __restrict__ g0,
    const float* __restrict__ be0,
    const float* __restrict__ b1,
    const float* __restrict__ th1,
    const float* __restrict__ g1,
    const float* __restrict__ be1,
    const short* __restrict__ wsp,      // pre-split weight planes
    float* __restrict__ out)
{
    __shared__ __align__(16) char lds[27648];
    short* ah = (short*)lds;                      // [32][72]  (GEMM1 staging)
    short* am = ah + 32 * A1S;
    short* al = am + 32 * A1S;
    float* zsq = (float*)lds;                     // [16][193] chunk z tile (aliases A1)
    short* a2h = (short*)(lds + 13824);           // [32][72]  layer-2 A planes
    short* a2m = a2h + 32 * A2S;
    short* a2l = a2m + 32 * A2S;

    const int tid = threadIdx.x;
    const long rowbase = (long)blockIdx.x * MB;

    float* out0 = out;                                      // h1      [T*B][64]
    float* out1 = out + (long)T_SEQ * B_BATCH * H_DIM;      // h0[-1]  [128][64]
    float* out2 = out1 + B_BATCH * H_DIM;                   // c0[-1]
    float* out3 = out2 + B_BATCH * H_DIM;                   // h1[-1]
    float* out4 = out3 + B_BATCH * H_DIM;                   // c1[-1]

    const int lane = tid & 63;
    const int wave = tid >> 6;
    const int ln   = lane & 15;   // MFMA m/n lane index
    const int quad = lane >> 4;   // MFMA k-group / row-group
    const int cw   = wave * 48;   // this wave's N-column base (192 cols / 4 waves)

    // B plane row offsets (in shorts) for this wave's 3 column-tiles
    int brow0[3], brow1[3];
    #pragma unroll
    for (int nt = 0; nt < 3; ++nt) {
        int gc = cw + nt * 16 + ln;
        brow0[nt] = gc * 512;
        brow1[nt] = gc * 64;
    }

    // staging geometry: each thread owns 8 contiguous cols of one row per K=64 chunk
    const int sr = tid >> 3;            // row 0..31
    const int sc = (tid & 7) << 3;      // col base 0,8,...,56
    const float* xrow = x + (rowbase + sr) * 512 + sc;
    const int sao = sr * A1S + sc;

    // ------- GEMM1: z0[32][192] = x[32][512] . W0g^T, K chunks of 64, async-staged
    f32x4 acc[2][3];
    #pragma unroll
    for (int mt = 0; mt < 2; ++mt)
        #pragma unroll
        for (int nt = 0; nt < 3; ++nt)
            acc[mt][nt] = (f32x4){0.f, 0.f, 0.f, 0.f};

    {   // prologue: stage chunk 0
        float4 f0 = *(const float4*)xrow;
        float4 f1 = *(const float4*)(xrow + 4);
        split8(f0, f1, ah, am, al, sao);
    }
    __syncthreads();

    for (int kc = 0; kc < 512; kc += 64) {
        // async-stage: issue next chunk's global loads BEFORE compute;
        // latency hides under the MFMA phase; split+write after the barrier.
        float4 n0, n1;
        const bool more = (kc + 64) < 512;
        if (more) {
            n0 = *(const float4*)(xrow + kc + 64);
            n1 = *(const float4*)(xrow + kc + 68);
        }
        #pragma unroll
        for (int k0 = 0; k0 < 64; k0 += 32) {
            int ka = k0 + quad * 8;
            bf16x8 Ah[2], Am[2], Al[2];
            #pragma unroll
            for (int mt = 0; mt < 2; ++mt) {
                int ao = (mt * 16 + ln) * A1S + ka;
                Ah[mt] = *(const bf16x8*)(ah + ao);
                Am[mt] = *(const bf16x8*)(am + ao);
                Al[mt] = *(const bf16x8*)(al + ao);
            }
            #pragma unroll
            for (int nt = 0; nt < 3; ++nt) {
                int bo = brow0[nt] + kc + ka;
                bf16x8 Bh = *(const bf16x8*)(wsp + W0H + bo);
                bf16x8 Bm = *(const bf16x8*)(wsp + W0M + bo);
                bf16x8 Bl = *(const bf16x8*)(wsp + W0L + bo);
                #pragma unroll
                for (int mt = 0; mt < 2; ++mt)
                    acc[mt][nt] = mfma6(Ah[mt], Am[mt], Al[mt], Bh, Bm, Bl, acc[mt][nt]);
            }
        }
        __syncthreads();   // plane reads done before overwrite / zsq write
        if (more) {
            split8(n0, n1, ah, am, al, sao);
            __syncthreads();
        }
    }

    // ------- layer 0: two 16-row chunks; frags passed BY VALUE (static regs, no
    // runtime indexing -> no scratch; this was r3's spill bug)
    auto l0chunk = [&](f32x4 f0, f32x4 f1, f32x4 f2, int cb) {
        // epilogue: D[m][n]: col = lane&15, row = quad*4 + reg  [measured m89/m91]
        #pragma unroll
        for (int i = 0; i < 4; ++i) {
            int ro = (quad * 4 + i) * ZQ_STRIDE + cw + ln;
            zsq[ro]      = f0[i];
            zsq[ro + 16] = f1[i];
            zsq[ro + 32] = f2[i];
        }
        __syncthreads();

        // cumprod(cos(z + b + th)): 48 chains (16 rows x 3 gates)
        if (tid < 48) {
            int gi = tid >> 4;
            int r  = tid & 15;
            float* zrow = zsq + r * ZQ_STRIDE + gi * 64;
            const float* bg = b0 + 64 + gi * 64;
            const float* tg = th0 + 64 + gi * 64;
            float p = 1.0f;
            for (int n = 0; n < 64; ++n) {
                p *= fast_cos(zrow[n] + bg[n] + tg[n]);
                zrow[n] = p;
            }
        }
        __syncthreads();

        // gates + two-pass LayerNorm -> registers -> split into A2 planes
        if (tid < 64) {
            int r = tid >> 2;            // row 0..15 within chunk
            int j = tid & 3;             // 16-element column chunk
            int rloc = cb + r;           // row within block tile (0..31)
            long tbrow = rowbase + rloc;
            bool lastt = (tbrow >= LASTROW);
            int bidx = (int)(tbrow - LASTROW);
            const float* zr = zsq + r * ZQ_STRIDE;
            float h[16];
            float s = 0.f;
            #pragma unroll
            for (int i = 0; i < 16; ++i) {
                int n = j * 16 + i;
                float q1 = zr[n];            // gate 1 (input)
                float q2 = zr[64 + n];       // gate 2 (update)
                float q3 = zr[128 + n];      // gate 3 (output)
                float ig = fast_sigmoid(q1);
                float gg = fast_tanh_pos(fast_sigmoid(q2));
                float og = fast_sigmoid(q3);
                float c  = ig * gg;
                float hv = og * fast_tanh_pos(c);
                h[i] = hv;
                s += hv;
                if (lastt) out2[bidx * 64 + n] = c;
            }
            s += __shfl_xor(s, 1);  s += __shfl_xor(s, 2);
            float mu = s * (1.0f / 64.0f);
            float s2 = 0.f;
            #pragma unroll
            for (int i = 0; i < 16; ++i) {           // two-pass: matches mean((h-mu)^2)
                float d = h[i] - mu;
                s2 += d * d;
            }
            s2 += __shfl_xor(s2, 1); s2 += __shfl_xor(s2, 2);
            float var = s2 * (1.0f / 64.0f);
            float rs  = rsqrtf(var + 1e-5f);
            float hl[16];
            #pragma unroll
            for (int i = 0; i < 16; ++i) {
                int n = j * 16 + i;
                hl[i] = (h[i] - mu) * rs * g0[n] + be0[n];
                if (lastt) out1[bidx * 64 + n] = hl[i];
            }
            // split ONCE into layer-2 A planes (A2 region disjoint from zsq)
            int ab = rloc * A2S + j * 16;
            uint4 Ph, Pm, Pl;
            tsplit2(hl[0], hl[1], Ph.x, Pm.x, Pl.x);
            tsplit2(hl[2], hl[3], Ph.y, Pm.y, Pl.y);
            tsplit2(hl[4], hl[5], Ph.z, Pm.z, Pl.z);
            tsplit2(hl[6], hl[7], Ph.w, Pm.w, Pl.w);
            *(uint4*)(a2h + ab) = Ph;
            *(uint4*)(a2m + ab) = Pm;
            *(uint4*)(a2l + ab) = Pl;
            tsplit2(hl[8],  hl[9],  Ph.x, Pm.x, Pl.x);
            tsplit2(hl[10], hl[11], Ph.y, Pm.y, Pl.y);
            tsplit2(hl[12], hl[13], Ph.z, Pm.z, Pl.z);
            tsplit2(hl[14], hl[15], Ph.w, Pm.w, Pl.w);
            *(uint4*)(a2h + ab + 8) = Ph;
            *(uint4*)(a2m + ab + 8) = Pm;
            *(uint4*)(a2l + ab + 8) = Pl;
        }
        __syncthreads();   // zsq reads done before next chunk overwrites; A2 visible
    };
    l0chunk(acc[0][0], acc[0][1], acc[0][2], 0);
    l0chunk(acc[1][0], acc[1][1], acc[1][2], 16);

    // ------- GEMM2: z1[32][192] = h0[32][64] . W1g^T, pre-split A2 planes, K=64
    f32x4 acc2[2][3];
    #pragma unroll
    for (int mt = 0; mt < 2; ++mt)
        #pragma unroll
        for (int nt = 0; nt < 3; ++nt)
            acc2[mt][nt] = (f32x4){0.f, 0.f, 0.f, 0.f};
    #pragma unroll
    for (int k0 = 0; k0 < 64; k0 += 32) {
        int ka = k0 + quad * 8;
        bf16x8 Ah[2], Am[2], Al[2];
        #pragma unroll
        for (int mt = 0; mt < 2; ++mt) {
            int ao = (mt * 16 + ln) * A2S + ka;
            Ah[mt] = *(const bf16x8*)(a2h + ao);
            Am[mt] = *(const bf16x8*)(a2m + ao);
            Al[mt] = *(const bf16x8*)(a2l + ao);
        }
        #pragma unroll
        for (int nt = 0; nt < 3; ++nt) {
            int bo = brow1[nt] + ka;
            bf16x8 Bh = *(const bf16x8*)(wsp + W1H + bo);
            bf16x8 Bm = *(const bf16x8*)(wsp + W1M + bo);
            bf16x8 Bl = *(const bf16x8*)(wsp + W1L + bo);
            #pragma unroll
            for (int mt = 0; mt < 2; ++mt)
                acc2[mt][nt] = mfma6(Ah[mt], Am[mt], Al[mt], Bh, Bm, Bl, acc2[mt][nt]);
        }
    }
    // no barrier needed: zsq (written next) is disjoint from A2 (read above), and
    // zsq's previous readers were fenced by l0chunk's trailing barrier

    // ------- layer 1: same two-chunk processing; gates write global directly
    auto l1chunk = [&](f32x4 f0, f32x4 f1, f32x4 f2, int cb) {
        #pragma unroll
        for (int i = 0; i < 4; ++i) {
            int ro = (quad * 4 + i) * ZQ_STRIDE + cw + ln;
            zsq[ro]      = f0[i];
            zsq[ro + 16] = f1[i];
            zsq[ro + 32] = f2[i];
        }
        __syncthreads();

        if (tid < 48) {
            int gi = tid >> 4;
            int r  = tid & 15;
            float* zrow = zsq + r * ZQ_STRIDE + gi * 64;
            const float* bg = b1 + 64 + gi * 64;
            const float* tg = th1 + 64 + gi * 64;
            float p = 1.0f;
            for (int n = 0; n < 64; ++n) {
                p *= fast_cos(zrow[n] + bg[n] + tg[n]);
                zrow[n] = p;
            }
        }
        __syncthreads();

        if (tid < 64) {
            int r = tid >> 2;
            int j = tid & 3;
            long tbrow = rowbase + cb + r;
            bool lastt = (tbrow >= LASTROW);
            int bidx = (int)(tbrow - LASTROW);
            const float* zr = zsq + r * ZQ_STRIDE;
            float h[16];
            float s = 0.f;
            #pragma unroll
            for (int i = 0; i < 16; ++i) {
                int n = j * 16 + i;
                float q1 = zr[n];
                float q2 = zr[64 + n];
                float q3 = zr[128 + n];
                float ig = fast_sigmoid(q1);
                float gg = fast_tanh_pos(fast_sigmoid(q2));
                float og = fast_sigmoid(q3);
                float c  = ig * gg;
                float hv = og * fast_tanh_pos(c);
                h[i] = hv;
                s += hv;
                if (lastt) out4[bidx * 64 + n] = c;
            }
            s += __shfl_xor(s, 1);  s += __shfl_xor(s, 2);
            float mu = s * (1.0f / 64.0f);
            float s2 = 0.f;
            #pragma unroll
            for (int i = 0; i < 16; ++i) {
                float d = h[i] - mu;
                s2 += d * d;
            }
            s2 += __shfl_xor(s2, 1); s2 += __shfl_xor(s2, 2);
            float var = s2 * (1.0f / 64.0f);
            float rs  = rsqrtf(var + 1e-5f);
            float o4[16];
            #pragma unroll
            for (int i = 0; i < 16; ++i)
                o4[i] = (h[i] - mu) * rs * g1[j * 16 + i] + be1[j * 16 + i];
            float* dst = out0 + tbrow * 64 + j * 16;
            #pragma unroll
            for (int i4 = 0; i4 < 4; ++i4)
                *(float4*)(dst + i4 * 4) = *(float4*)(o4 + i4 * 4);
            if (lastt) {
                float* dst3 = out3 + (long)bidx * 64 + j * 16;
                #pragma unroll
                for (int i4 = 0; i4 < 4; ++i4)
                    *(float4*)(dst3 + i4 * 4) = *(float4*)(o4 + i4 * 4);
            }
        }
        __syncthreads();
    };
    l1chunk(acc2[0][0], acc2[0][1], acc2[0][2], 0);
    l1chunk(acc2[1][0], acc2[1][1], acc2[1][2], 16);
}

extern "C" void kernel_launch(void* const* d_in, const int* in_sizes, int n_in,
                              void* d_out, int out_size, void* d_ws, size_t ws_size,
                              hipStream_t stream) {
    const float* x   = (const float*)d_in[0];
    const float* W0  = (const float*)d_in[1];
    const float* b0  = (const float*)d_in[2];
    const float* th0 = (const float*)d_in[3];
    const float* g0  = (const float*)d_in[4];
    const float* be0 = (const float*)d_in[5];
    const float* W1  = (const float*)d_in[6];
    const float* b1  = (const float*)d_in[7];
    const float* th1 = (const float*)d_in[8];
    const float* g1  = (const float*)d_in[9];
    const float* be1 = (const float*)d_in[10];
    short* wsp = (short*)d_ws;     // needs 663552 B

    presplit_w<<<dim3(432), dim3(256), 0, stream>>>(W0, W1, wsp);
    qlstm_fused<<<dim3(2048), dim3(256), 0, stream>>>(
        x, b0, th0, g0, be0, b1, th1, g1, be1, wsp, (float*)d_out);
}

// Round 5
// 314.053 us; speedup vs baseline: 1.3018x; 1.3008x over previous
//
#include <hip/hip_runtime.h>
#include <hip/hip_bf16.h>

typedef __attribute__((ext_vector_type(8))) short bf16x8;
typedef __attribute__((ext_vector_type(4))) float f32x4;

#define T_SEQ   512
#define B_BATCH 128
#define H_DIM   64
#define MB      64               // rows (t*B+b) per block
#define A1S     72               // bf16 per row of A split-plane (64 + 8 pad; 144B = 9x16B)
#define ZS_STRIDE 193            // f32 per row of z tile (192 + 1 pad)
#define A2S       72             // bf16 per row of layer-2 A split-plane
#define LASTROW ((T_SEQ - 1) * B_BATCH)   // 65408

// ws layout (shorts): W0 gate-rows (192x512) planes h/m/l, then W1 (192x64) h/m/l
#define W0H 0
#define W0M 98304
#define W0L 196608
#define W1H 294912
#define W1M 307200
#define W1L 319488
// total 331776 shorts = 663552 bytes of d_ws

// truncation 3-way split: f = h + m + l + r, |r| <= ~2^-24 |f|; subtractions exact
__device__ __forceinline__ void tsplit(float f, unsigned& h, unsigned& m, unsigned& l) {
    unsigned uf = __builtin_bit_cast(unsigned, f);
    h = uf >> 16;
    float hf = __builtin_bit_cast(float, uf & 0xFFFF0000u);
    float r1 = f - hf;
    unsigned u1 = __builtin_bit_cast(unsigned, r1);
    m = u1 >> 16;
    float mf = __builtin_bit_cast(float, u1 & 0xFFFF0000u);
    float r2 = r1 - mf;
    l = __builtin_bit_cast(unsigned, r2) >> 16;
}

// split two floats, pack into one dword per plane (elem0 low, elem1 high)
__device__ __forceinline__ void tsplit2(float a, float b,
                                        unsigned& ph, unsigned& pm, unsigned& pl) {
    unsigned ha, ma, la, hb, mb, lb;
    tsplit(a, ha, ma, la);
    tsplit(b, hb, mb, lb);
    ph = ha | (hb << 16);
    pm = ma | (mb << 16);
    pl = la | (lb << 16);
}

// split 16 floats (4 float4) into 3 planes at shorts-offset ao (row-contiguous 16 cols)
__device__ __forceinline__ void split16(const float4 f[4],
                                        short* __restrict__ ah, short* __restrict__ am,
                                        short* __restrict__ al, int ao) {
    uint4 Ph, Pm, Pl;
    tsplit2(f[0].x, f[0].y, Ph.x, Pm.x, Pl.x);
    tsplit2(f[0].z, f[0].w, Ph.y, Pm.y, Pl.y);
    tsplit2(f[1].x, f[1].y, Ph.z, Pm.z, Pl.z);
    tsplit2(f[1].z, f[1].w, Ph.w, Pm.w, Pl.w);
    *(uint4*)(ah + ao) = Ph;
    *(uint4*)(am + ao) = Pm;
    *(uint4*)(al + ao) = Pl;
    tsplit2(f[2].x, f[2].y, Ph.x, Pm.x, Pl.x);
    tsplit2(f[2].z, f[2].w, Ph.y, Pm.y, Pl.y);
    tsplit2(f[3].x, f[3].y, Ph.z, Pm.z, Pl.z);
    tsplit2(f[3].z, f[3].w, Ph.w, Pm.w, Pl.w);
    *(uint4*)(ah + ao + 8) = Ph;
    *(uint4*)(am + ao + 8) = Pm;
    *(uint4*)(al + ao + 8) = Pl;
}

// 6-product accumulate: (h1+m1+l1)(h2+m2+l2), dropping ml, lm, ll (~2^-24 |ab|)
__device__ __forceinline__ f32x4 mfma6(bf16x8 ah, bf16x8 am, bf16x8 al,
                                       bf16x8 bh, bf16x8 bm, bf16x8 bl, f32x4 c) {
    c = __builtin_amdgcn_mfma_f32_16x16x32_bf16(ah, bh, c, 0, 0, 0);
    c = __builtin_amdgcn_mfma_f32_16x16x32_bf16(ah, bm, c, 0, 0, 0);
    c = __builtin_amdgcn_mfma_f32_16x16x32_bf16(am, bh, c, 0, 0, 0);
    c = __builtin_amdgcn_mfma_f32_16x16x32_bf16(ah, bl, c, 0, 0, 0);
    c = __builtin_amdgcn_mfma_f32_16x16x32_bf16(al, bh, c, 0, 0, 0);
    c = __builtin_amdgcn_mfma_f32_16x16x32_bf16(am, bm, c, 0, 0, 0);
    return c;
}

// branch-free Cody-Waite cos, ~1 ulp for |x| <~ 30 (args here are |z+bt| <~ 9).
__device__ __forceinline__ float fast_cos(float x) {
    float n = rintf(x * 0.6366197723675814f);          // 2/pi
    int   m = (int)n;
    float r = __builtin_fmaf(n, -1.5707962512969971e+00f, x);
    r = __builtin_fmaf(n, -7.5497894158615964e-08f, r);
    r = __builtin_fmaf(n, -5.3903025299577647e-15f, r);
    float r2 = r * r;
    float ps = __builtin_fmaf(r2, 2.7557314297e-06f, -1.9841270114e-04f);
    ps = __builtin_fmaf(r2, ps, 8.3333337680e-03f);
    ps = __builtin_fmaf(r2, ps, -1.6666667163e-01f);
    float s = __builtin_fmaf(r * r2, ps, r);
    float pc = __builtin_fmaf(r2, 2.4801587642e-05f, -1.3888889225e-03f);
    pc = __builtin_fmaf(r2, pc, 4.1666667908e-02f);
    pc = __builtin_fmaf(r2, pc, -0.5f);
    float c = __builtin_fmaf(r2, pc, 1.0f);
    float v = (m & 1) ? s : c;
    unsigned sign = (unsigned)((m + 1) & 2) << 30;     // 0 or 0x80000000
    return __builtin_bit_cast(float, __builtin_bit_cast(unsigned, v) ^ sign);
}

// sigmoid via native v_exp (~2 ulp) + hw rcp with one Newton step
__device__ __forceinline__ float fast_sigmoid(float x) {
    float e = __expf(-x);
    float d = 1.0f + e;
    float r = __builtin_amdgcn_rcpf(d);
    return r * (2.0f - d * r);
}

// tanh for x >= 0 (args here are in (0,1)): (e^2x - 1)/(e^2x + 1); abs err ~2e-7
__device__ __forceinline__ float fast_tanh_pos(float x) {
    float t = __expf(2.0f * x);
    float d = t + 1.0f;
    float r = __builtin_amdgcn_rcpf(d);
    r = r * (2.0f - d * r);
    return (t - 1.0f) * r;
}

// ---------- kernel 1: pre-split weights into d_ws (runs every launch; ~5 us) ----------
__global__ __launch_bounds__(256) void presplit_w(const float* __restrict__ W0,
                                                  const float* __restrict__ W1,
                                                  short* __restrict__ ws) {
    int i = blockIdx.x * 256 + threadIdx.x;
    if (i < 98304) {                      // W0 gates 1..3: flat rows 64..255, stride 576
        int r = i >> 9, k = i & 511;
        unsigned h, m, l;
        tsplit(W0[(r + 64) * 576 + k], h, m, l);
        ws[W0H + i] = (short)h;
        ws[W0M + i] = (short)m;
        ws[W0L + i] = (short)l;
    } else if (i < 110592) {              // W1 gates 1..3: rows 64..255, stride 128, k<64
        int j = i - 98304;
        int r = j >> 6, k = j & 63;
        unsigned h, m, l;
        tsplit(W1[(r + 64) * 128 + k], h, m, l);
        ws[W1H + j] = (short)h;
        ws[W1M + j] = (short)m;
        ws[W1L + j] = (short)l;
    }
}

// ---------- kernel 2: fused QLSTM (MB=64, grid 1024) ----------
// LDS layout (total 78592 B -> 2 blocks/CU):
//   [0, 55296)       A1 split-plane DOUBLE buffer: buf b at b*27648,
//                    planes ah/am/al [64][72] bf16 (3 x 9216 each) -- GEMM1 only
//   [0, 49408)       zs [64][193] f32  (aliases A1 bufs; written after GEMM1)
//   [49408, 77056)   A2 split-planes [64][72] bf16 x3 (disjoint from zs!)
//   [77056, 78592)   bt0[192], bt1[192] f32 (b+th, gates 1..3)
__global__ __launch_bounds__(256, 2) void qlstm_fused(
    const float* __restrict__ x,
    const float* __restrict__ b0,
    const float* __restrict__ th0,
    const float* __restrict__ g0,
    const float* __restrict__ be0,
    const float* __restrict__ b1,
    const float* __restrict__ th1,
    const float* __restrict__ g1,
    const float* __restrict__ be1,
    const short* __restrict__ wsp,      // pre-split weight planes
    float* __restrict__ out)
{
    __shared__ __align__(16) char lds[78592];
    short* ah0 = (short*)lds;                     // buf0 planes
    short* am0 = ah0 + 4608;
    short* al0 = am0 + 4608;
    short* ah1 = (short*)(lds + 27648);           // buf1 planes
    short* am1 = ah1 + 4608;
    short* al1 = am1 + 4608;
    float* zs  = (float*)lds;                     // [64][193] (aliases A1 bufs)
    short* a2h = (short*)(lds + 49408);           // [64][72] layer-2 A planes
    short* a2m = a2h + 4608;
    short* a2l = a2m + 4608;
    float* bt0 = (float*)(lds + 77056);           // [192]
    float* bt1 = bt0 + 192;                       // [192]

    const int tid = threadIdx.x;
    const long rowbase = (long)blockIdx.x * MB;

    float* out0 = out;                                      // h1      [T*B][64]
    float* out1 = out + (long)T_SEQ * B_BATCH * H_DIM;      // h0[-1]  [128][64]
    float* out2 = out1 + B_BATCH * H_DIM;                   // c0[-1]
    float* out3 = out2 + B_BATCH * H_DIM;                   // h1[-1]
    float* out4 = out3 + B_BATCH * H_DIM;                   // c1[-1]

    // stage combined bias + theta for gates 1..3 (flat row in (4,64) = 64 + gc)
    if (tid < 192) {
        bt0[tid] = b0[64 + tid] + th0[64 + tid];
        bt1[tid] = b1[64 + tid] + th1[64 + tid];
    }

    const int lane = tid & 63;
    const int wave = tid >> 6;
    const int ln   = lane & 15;   // MFMA m/n lane index
    const int quad = lane >> 4;   // MFMA k-group / row-group
    const int cw   = wave * 48;   // this wave's N-column base (192 cols / 4 waves)

    // B plane row offsets (in shorts) for this wave's 3 column-tiles
    int brow0[3], brow1[3];
    #pragma unroll
    for (int nt = 0; nt < 3; ++nt) {
        int gc = cw + nt * 16 + ln;
        brow0[nt] = gc * 512;
        brow1[nt] = gc * 64;
    }

    // staging geometry: each thread owns 16 contiguous cols of one row per K=64 chunk
    const int sr = tid >> 2;            // row 0..63
    const int sc = (tid & 3) << 4;      // col base 0,16,32,48
    const float* xrow = x + (rowbase + sr) * 512 + sc;
    const int sao = sr * A1S + sc;

    // ------- GEMM1: z0[64][192] = x[64][512] . W0g^T, K chunks of 64,
    // DOUBLE-BUFFERED planes: one barrier per chunk; split of next chunk
    // overlaps MFMA of current (no dependency, no intervening barrier).
    f32x4 acc[4][3];
    #pragma unroll
    for (int mt = 0; mt < 4; ++mt)
        #pragma unroll
        for (int nt = 0; nt < 3; ++nt)
            acc[mt][nt] = (f32x4){0.f, 0.f, 0.f, 0.f};

    {   // prologue: stage chunk 0 into buf0
        float4 f[4];
        #pragma unroll
        for (int u = 0; u < 4; ++u) f[u] = *(const float4*)(xrow + u * 4);
        split16(f, ah0, am0, al0, sao);
    }
    __syncthreads();

    for (int kc = 0; kc < 512; kc += 64) {
        const int p = (kc >> 6) & 1;
        short* rah = p ? ah1 : ah0;     // read buffer (chunk kc)
        short* ram = p ? am1 : am0;
        short* ral = p ? al1 : al0;
        short* wah = p ? ah0 : ah1;     // write buffer (chunk kc+64)
        short* wam = p ? am0 : am1;
        short* wal = p ? al0 : al1;

        // issue next chunk's global loads first; latency hides under MFMA issue
        float4 nf[4];
        const bool more = (kc + 64) < 512;
        if (more) {
            #pragma unroll
            for (int u = 0; u < 4; ++u)
                nf[u] = *(const float4*)(xrow + kc + 64 + u * 4);
        }
        // MFMA phase on read buffer
        #pragma unroll
        for (int k0 = 0; k0 < 64; k0 += 32) {
            int ka = k0 + quad * 8;
            bf16x8 Ah[4], Am[4], Al[4];
            #pragma unroll
            for (int mt = 0; mt < 4; ++mt) {
                int ao = (mt * 16 + ln) * A1S + ka;
                Ah[mt] = *(const bf16x8*)(rah + ao);
                Am[mt] = *(const bf16x8*)(ram + ao);
                Al[mt] = *(const bf16x8*)(ral + ao);
            }
            #pragma unroll
            for (int nt = 0; nt < 3; ++nt) {
                int bo = brow0[nt] + kc + ka;
                bf16x8 Bh = *(const bf16x8*)(wsp + W0H + bo);
                bf16x8 Bm = *(const bf16x8*)(wsp + W0M + bo);
                bf16x8 Bl = *(const bf16x8*)(wsp + W0L + bo);
                #pragma unroll
                for (int mt = 0; mt < 4; ++mt)
                    acc[mt][nt] = mfma6(Ah[mt], Am[mt], Al[mt], Bh, Bm, Bl, acc[mt][nt]);
            }
        }
        // split next chunk into the OTHER buffer: its previous readers (MFMAs of
        // chunk kc-64) finished before the barrier that ended iteration kc-64.
        if (more) split16(nf, wah, wam, wal, sao);
        __syncthreads();
    }

    // ------- epilogue: D[m][n]: col = lane&15, row = quad*4 + reg  [m89/m91]
    // A1 bufs dead (last MFMA reads fenced by final loop barrier); zs aliases them.
    #pragma unroll
    for (int mt = 0; mt < 4; ++mt)
        #pragma unroll
        for (int nt = 0; nt < 3; ++nt)
            #pragma unroll
            for (int i = 0; i < 4; ++i) {
                int row = mt * 16 + quad * 4 + i;
                int col = cw + nt * 16 + ln;
                zs[row * ZS_STRIDE + col] = acc[mt][nt][i];
            }
    __syncthreads();

    // ------- cumprod(cos(z + b + th)) layer 0 (192 chains, wave 3 idles)
    if (tid < 192) {
        int gi = tid >> 6;
        int r  = tid & 63;
        float* zrow = zs + r * ZS_STRIDE + gi * 64;
        const float* btg = bt0 + gi * 64;
        float p = 1.0f;
        for (int n = 0; n < 64; ++n) {
            p *= fast_cos(zrow[n] + btg[n]);
            zrow[n] = p;
        }
    }
    __syncthreads();

    // ------- gates + two-pass LayerNorm layer 0 -> A2 planes (disjoint from zs:
    // no internal barrier needed)
    {
        int r = tid >> 2;            // row 0..63
        int j = tid & 3;             // 16-element chunk
        long tbrow = rowbase + r;
        bool lastt = (tbrow >= LASTROW);
        int bidx = (int)(tbrow - LASTROW);
        const float* zr = zs + r * ZS_STRIDE;
        float h[16];
        float s = 0.f;
        #pragma unroll
        for (int i = 0; i < 16; ++i) {
            int n = j * 16 + i;
            float q1 = zr[n];            // gate 1 (input)
            float q2 = zr[64 + n];       // gate 2 (update)
            float q3 = zr[128 + n];      // gate 3 (output)
            float ig = fast_sigmoid(q1);
            float gg = fast_tanh_pos(fast_sigmoid(q2));
            float og = fast_sigmoid(q3);
            float c  = ig * gg;
            float hv = og * fast_tanh_pos(c);
            h[i] = hv;
            s += hv;
            if (lastt) out2[bidx * 64 + n] = c;
        }
        s += __shfl_xor(s, 1);  s += __shfl_xor(s, 2);
        float mu = s * (1.0f / 64.0f);
        float s2 = 0.f;
        #pragma unroll
        for (int i = 0; i < 16; ++i) {           // two-pass: matches mean((h-mu)^2)
            float d = h[i] - mu;
            s2 += d * d;
        }
        s2 += __shfl_xor(s2, 1); s2 += __shfl_xor(s2, 2);
        float var = s2 * (1.0f / 64.0f);
        float rs  = rsqrtf(var + 1e-5f);
        float hl[16];
        #pragma unroll
        for (int i = 0; i < 16; ++i) {
            int n = j * 16 + i;
            hl[i] = (h[i] - mu) * rs * g0[n] + be0[n];
            if (lastt) out1[bidx * 64 + n] = hl[i];
        }
        // split ONCE into layer-2 A planes
        int ab = r * A2S + j * 16;
        uint4 Ph, Pm, Pl;
        tsplit2(hl[0], hl[1], Ph.x, Pm.x, Pl.x);
        tsplit2(hl[2], hl[3], Ph.y, Pm.y, Pl.y);
        tsplit2(hl[4], hl[5], Ph.z, Pm.z, Pl.z);
        tsplit2(hl[6], hl[7], Ph.w, Pm.w, Pl.w);
        *(uint4*)(a2h + ab) = Ph;
        *(uint4*)(a2m + ab) = Pm;
        *(uint4*)(a2l + ab) = Pl;
        tsplit2(hl[8],  hl[9],  Ph.x, Pm.x, Pl.x);
        tsplit2(hl[10], hl[11], Ph.y, Pm.y, Pl.y);
        tsplit2(hl[12], hl[13], Ph.z, Pm.z, Pl.z);
        tsplit2(hl[14], hl[15], Ph.w, Pm.w, Pl.w);
        *(uint4*)(a2h + ab + 8) = Ph;
        *(uint4*)(a2m + ab + 8) = Pm;
        *(uint4*)(a2l + ab + 8) = Pl;
    }
    __syncthreads();   // A2 complete before GEMM2 reads

    // ------- GEMM2: z1[64][192] = h0[64][64] . W1g^T, pre-split A2 planes, K=64
    f32x4 acc2[4][3];
    #pragma unroll
    for (int mt = 0; mt < 4; ++mt)
        #pragma unroll
        for (int nt = 0; nt < 3; ++nt)
            acc2[mt][nt] = (f32x4){0.f, 0.f, 0.f, 0.f};
    #pragma unroll
    for (int k0 = 0; k0 < 64; k0 += 32) {
        int ka = k0 + quad * 8;
        bf16x8 Ah[4], Am[4], Al[4];
        #pragma unroll
        for (int mt = 0; mt < 4; ++mt) {
            int ao = (mt * 16 + ln) * A2S + ka;
            Ah[mt] = *(const bf16x8*)(a2h + ao);
            Am[mt] = *(const bf16x8*)(a2m + ao);
            Al[mt] = *(const bf16x8*)(a2l + ao);
        }
        #pragma unroll
        for (int nt = 0; nt < 3; ++nt) {
            int bo = brow1[nt] + ka;
            bf16x8 Bh = *(const bf16x8*)(wsp + W1H + bo);
            bf16x8 Bm = *(const bf16x8*)(wsp + W1M + bo);
            bf16x8 Bl = *(const bf16x8*)(wsp + W1L + bo);
            #pragma unroll
            for (int mt = 0; mt < 4; ++mt)
                acc2[mt][nt] = mfma6(Ah[mt], Am[mt], Al[mt], Bh, Bm, Bl, acc2[mt][nt]);
        }
    }
    // epilogue2 writes zs (disjoint from A2; zs's last readers fenced above):
    // no barrier needed between GEMM2 and this write.
    #pragma unroll
    for (int mt = 0; mt < 4; ++mt)
        #pragma unroll
        for (int nt = 0; nt < 3; ++nt)
            #pragma unroll
            for (int i = 0; i < 4; ++i) {
                int row = mt * 16 + quad * 4 + i;
                int col = cw + nt * 16 + ln;
                zs[row * ZS_STRIDE + col] = acc2[mt][nt][i];
            }
    __syncthreads();

    // ------- cumprod layer 1
    if (tid < 192) {
        int gi = tid >> 6;
        int r  = tid & 63;
        float* zrow = zs + r * ZS_STRIDE + gi * 64;
        const float* btg = bt1 + gi * 64;
        float p = 1.0f;
        for (int n = 0; n < 64; ++n) {
            p *= fast_cos(zrow[n] + btg[n]);
            zrow[n] = p;
        }
    }
    __syncthreads();

    // ------- gates + two-pass LayerNorm layer 1 -> out0 directly (+ out3/out4)
    {
        int r = tid >> 2;
        int j = tid & 3;
        long tbrow = rowbase + r;
        bool lastt = (tbrow >= LASTROW);
        int bidx = (int)(tbrow - LASTROW);
        const float* zr = zs + r * ZS_STRIDE;
        float h[16];
        float s = 0.f;
        #pragma unroll
        for (int i = 0; i < 16; ++i) {
            int n = j * 16 + i;
            float q1 = zr[n];
            float q2 = zr[64 + n];
            float q3 = zr[128 + n];
            float ig = fast_sigmoid(q1);
            float gg = fast_tanh_pos(fast_sigmoid(q2));
            float og = fast_sigmoid(q3);
            float c  = ig * gg;
            float hv = og * fast_tanh_pos(c);
            h[i] = hv;
            s += hv;
            if (lastt) out4[bidx * 64 + n] = c;
        }
        s += __shfl_xor(s, 1);  s += __shfl_xor(s, 2);
        float mu = s * (1.0f / 64.0f);
        float s2 = 0.f;
        #pragma unroll
        for (int i = 0; i < 16; ++i) {
            float d = h[i] - mu;
            s2 += d * d;
        }
        s2 += __shfl_xor(s2, 1); s2 += __shfl_xor(s2, 2);
        float var = s2 * (1.0f / 64.0f);
        float rs  = rsqrtf(var + 1e-5f);
        float o4[16];
        #pragma unroll
        for (int i = 0; i < 16; ++i)
            o4[i] = (h[i] - mu) * rs * g1[j * 16 + i] + be1[j * 16 + i];
        float* dst = out0 + tbrow * 64 + j * 16;
        #pragma unroll
        for (int i4 = 0; i4 < 4; ++i4)
            *(float4*)(dst + i4 * 4) = *(float4*)(o4 + i4 * 4);
        if (lastt) {
            float* dst3 = out3 + (long)bidx * 64 + j * 16;
            #pragma unroll
            for (int i4 = 0; i4 < 4; ++i4)
                *(float4*)(dst3 + i4 * 4) = *(float4*)(o4 + i4 * 4);
        }
    }
}

extern "C" void kernel_launch(void* const* d_in, const int* in_sizes, int n_in,
                              void* d_out, int out_size, void* d_ws, size_t ws_size,
                              hipStream_t stream) {
    const float* x   = (const float*)d_in[0];
    const float* W0  = (const float*)d_in[1];
    const float* b0  = (const float*)d_in[2];
    const float* th0 = (const float*)d_in[3];
    const float* g0  = (const float*)d_in[4];
    const float* be0 = (const float*)d_in[5];
    const float* W1  = (const float*)d_in[6];
    const float* b1  = (const float*)d_in[7];
    const float* th1 = (const float*)d_in[8];
    const float* g1  = (const float*)d_in[9];
    const float* be1 = (const float*)d_in[10];
    short* wsp = (short*)d_ws;     // needs 663552 B

    presplit_w<<<dim3(432), dim3(256), 0, stream>>>(W0, W1, wsp);
    qlstm_fused<<<dim3(1024), dim3(256), 0, stream>>>(
        x, b0, th0, g0, be0, b1, th1, g1, be1, wsp, (float*)d_out);
}

// Round 7
// 296.968 us; speedup vs baseline: 1.3767x; 1.0575x over previous
//
#include <hip/hip_runtime.h>
#include <hip/hip_bf16.h>

typedef __attribute__((ext_vector_type(8))) short bf16x8;
typedef __attribute__((ext_vector_type(4))) float f32x4;

#define T_SEQ   512
#define B_BATCH 128
#define H_DIM   64
#define MB      64               // rows (t*B+b) per block
#define A1S     72               // bf16 per row of A split-plane (64 + 8 pad; 144B = 9x16B)
#define ZS_STRIDE 193            // f32 per row of z tile (192 + 1 pad)
#define A2S       72             // bf16 per row of layer-2 A split-plane
#define LASTROW ((T_SEQ - 1) * B_BATCH)   // 65408

// ws layout (shorts), FRAGMENT-PACKED so every MFMA B-load is lane-coalesced:
//   W0: tile(wave,kc,k0,nt) at ((wave*8+kc)*2+k0)*3+nt, 3 planes x 512 shorts each;
//       within plane: lane*8 + e  (lane = quad*16+ln; covers B[gc][col..col+8),
//       gc = wave*48+nt*16+ln, col = kc*64+k0*32+quad*8)
//   W0 total 192 tile-triples * 1536 = 294912 shorts; W1 at W1P, 24 triples.
#define W1P 294912
// total 331776 shorts = 663552 bytes of d_ws

// truncation 3-way split: f = h + m + l + r, |r| <= ~2^-24 |f|; subtractions exact
__device__ __forceinline__ void tsplit(float f, unsigned& h, unsigned& m, unsigned& l) {
    unsigned uf = __builtin_bit_cast(unsigned, f);
    h = uf >> 16;
    float hf = __builtin_bit_cast(float, uf & 0xFFFF0000u);
    float r1 = f - hf;
    unsigned u1 = __builtin_bit_cast(unsigned, r1);
    m = u1 >> 16;
    float mf = __builtin_bit_cast(float, u1 & 0xFFFF0000u);
    float r2 = r1 - mf;
    l = __builtin_bit_cast(unsigned, r2) >> 16;
}

// split two floats, pack into one dword per plane (elem0 low, elem1 high)
__device__ __forceinline__ void tsplit2(float a, float b,
                                        unsigned& ph, unsigned& pm, unsigned& pl) {
    unsigned ha, ma, la, hb, mb, lb;
    tsplit(a, ha, ma, la);
    tsplit(b, hb, mb, lb);
    ph = ha | (hb << 16);
    pm = ma | (mb << 16);
    pl = la | (lb << 16);
}

// split 16 floats (4 float4) into 3 planes at shorts-offset ao (row-contiguous 16 cols)
__device__ __forceinline__ void split16(const float4 f[4],
                                        short* __restrict__ ah, short* __restrict__ am,
                                        short* __restrict__ al, int ao) {
    uint4 Ph, Pm, Pl;
    tsplit2(f[0].x, f[0].y, Ph.x, Pm.x, Pl.x);
    tsplit2(f[0].z, f[0].w, Ph.y, Pm.y, Pl.y);
    tsplit2(f[1].x, f[1].y, Ph.z, Pm.z, Pl.z);
    tsplit2(f[1].z, f[1].w, Ph.w, Pm.w, Pl.w);
    *(uint4*)(ah + ao) = Ph;
    *(uint4*)(am + ao) = Pm;
    *(uint4*)(al + ao) = Pl;
    tsplit2(f[2].x, f[2].y, Ph.x, Pm.x, Pl.x);
    tsplit2(f[2].z, f[2].w, Ph.y, Pm.y, Pl.y);
    tsplit2(f[3].x, f[3].y, Ph.z, Pm.z, Pl.z);
    tsplit2(f[3].z, f[3].w, Ph.w, Pm.w, Pl.w);
    *(uint4*)(ah + ao + 8) = Ph;
    *(uint4*)(am + ao + 8) = Pm;
    *(uint4*)(al + ao + 8) = Pl;
}

// 6-product accumulate: (h1+m1+l1)(h2+m2+l2), dropping ml, lm, ll (~2^-24 |ab|)
__device__ __forceinline__ f32x4 mfma6(bf16x8 ah, bf16x8 am, bf16x8 al,
                                       bf16x8 bh, bf16x8 bm, bf16x8 bl, f32x4 c) {
    c = __builtin_amdgcn_mfma_f32_16x16x32_bf16(ah, bh, c, 0, 0, 0);
    c = __builtin_amdgcn_mfma_f32_16x16x32_bf16(ah, bm, c, 0, 0, 0);
    c = __builtin_amdgcn_mfma_f32_16x16x32_bf16(am, bh, c, 0, 0, 0);
    c = __builtin_amdgcn_mfma_f32_16x16x32_bf16(ah, bl, c, 0, 0, 0);
    c = __builtin_amdgcn_mfma_f32_16x16x32_bf16(al, bh, c, 0, 0, 0);
    c = __builtin_amdgcn_mfma_f32_16x16x32_bf16(am, bm, c, 0, 0, 0);
    return c;
}

// branch-free Cody-Waite cos, ~1 ulp for |x| <~ 30 (args here are |z+bt| <~ 9).
__device__ __forceinline__ float fast_cos(float x) {
    float n = rintf(x * 0.6366197723675814f);          // 2/pi
    int   m = (int)n;
    float r = __builtin_fmaf(n, -1.5707962512969971e+00f, x);
    r = __builtin_fmaf(n, -7.5497894158615964e-08f, r);
    r = __builtin_fmaf(n, -5.3903025299577647e-15f, r);
    float r2 = r * r;
    float ps = __builtin_fmaf(r2, 2.7557314297e-06f, -1.9841270114e-04f);
    ps = __builtin_fmaf(r2, ps, 8.3333337680e-03f);
    ps = __builtin_fmaf(r2, ps, -1.6666667163e-01f);
    float s = __builtin_fmaf(r * r2, ps, r);
    float pc = __builtin_fmaf(r2, 2.4801587642e-05f, -1.3888889225e-03f);
    pc = __builtin_fmaf(r2, pc, 4.1666667908e-02f);
    pc = __builtin_fmaf(r2, pc, -0.5f);
    float c = __builtin_fmaf(r2, pc, 1.0f);
    float v = (m & 1) ? s : c;
    unsigned sign = (unsigned)((m + 1) & 2) << 30;     // 0 or 0x80000000
    return __builtin_bit_cast(float, __builtin_bit_cast(unsigned, v) ^ sign);
}

// sigmoid via native v_exp (~2 ulp) + hw rcp with one Newton step
__device__ __forceinline__ float fast_sigmoid(float x) {
    float e = __expf(-x);
    float d = 1.0f + e;
    float r = __builtin_amdgcn_rcpf(d);
    return r * (2.0f - d * r);
}

// tanh for x >= 0 (args here are in (0,1)): (e^2x - 1)/(e^2x + 1); abs err ~2e-7
__device__ __forceinline__ float fast_tanh_pos(float x) {
    float t = __expf(2.0f * x);
    float d = t + 1.0f;
    float r = __builtin_amdgcn_rcpf(d);
    r = r * (2.0f - d * r);
    return (t - 1.0f) * r;
}

// ---------- kernel 1: pack + split weights into fragment order (~5 us) ----------
__global__ __launch_bounds__(256) void presplit_w(const float* __restrict__ W0,
                                                  const float* __restrict__ W1,
                                                  short* __restrict__ ws) {
    int i = blockIdx.x * 256 + threadIdx.x;
    if (i < 98304) {            // W0: (wave,kc,k0,nt,lane,e)
        int e  = i & 7;
        int l  = (i >> 3) & 63;
        int r  = i >> 9;        // 0..191
        int nt = r % 3;
        int r2 = r / 3;         // 0..63
        int k0 = r2 & 1;
        int r3 = r2 >> 1;       // 0..31
        int kc = r3 & 7;
        int wv = r3 >> 3;       // 0..3
        int gc  = wv * 48 + nt * 16 + (l & 15);
        int col = kc * 64 + k0 * 32 + (l >> 4) * 8 + e;
        unsigned h, m, lo;
        tsplit(W0[(64 + gc) * 576 + col], h, m, lo);
        int base = (((wv * 8 + kc) * 2 + k0) * 3 + nt) * 1536 + l * 8 + e;
        ws[base]        = (short)h;
        ws[base + 512]  = (short)m;
        ws[base + 1024] = (short)lo;
    } else if (i < 110592) {    // W1: (wave,k0,nt,lane,e)
        int j  = i - 98304;
        int e  = j & 7;
        int l  = (j >> 3) & 63;
        int r  = j >> 9;        // 0..23
        int nt = r % 3;
        int r2 = r / 3;         // 0..7
        int k0 = r2 & 1;
        int wv = r2 >> 1;       // 0..3
        int gc  = wv * 48 + nt * 16 + (l & 15);
        int col = k0 * 32 + (l >> 4) * 8 + e;
        unsigned h, m, lo;
        tsplit(W1[(64 + gc) * 128 + col], h, m, lo);
        int base = W1P + ((wv * 2 + k0) * 3 + nt) * 1536 + l * 8 + e;
        ws[base]        = (short)h;
        ws[base + 512]  = (short)m;
        ws[base + 1024] = (short)lo;
    }
}

// ---------- kernel 2: fused QLSTM (r2 structure + packed-B) ----------
// LDS layout (total 50944 B):
//   [0, 49408)      union: A1 split-planes ah/am/al [64][72] bf16 (3 x 9216)
//                          | zs [64][193] f32 (49408)
//                          | A2 split-planes [64][72] bf16 x3 (27648)
//   [49408, 50176)  bt0 [192] f32   (b0+th0, gates 1..3)
//   [50176, 50944)  bt1 [192] f32
__global__ __launch_bounds__(256, 3) void qlstm_fused(
    const float* __restrict__ x,
    const float* __restrict__ b0,
    const float* __restrict__ th0,
    const float* __restrict__ g0,
    const float* __restrict__ be0,
    const float* __restrict__ b1,
    const float* __restrict__ th1,
    const float* __restrict__ g1,
    const float* __restrict__ be1,
    const short* __restrict__ wsp,      // fragment-packed weight planes
    float* __restrict__ out)
{
    __shared__ __align__(16) char lds[50944];
    short* ah = (short*)lds;                      // [64][72]
    short* am = ah + 64 * A1S;
    short* al = am + 64 * A1S;
    float* zs  = (float*)lds;                     // [64][193] (aliases planes)
    short* a2h = (short*)lds;                     // [64][72]  (aliases zs; layer-2 A)
    short* a2m = a2h + 64 * A2S;
    short* a2l = a2m + 64 * A2S;
    float* bt0 = (float*)(lds + 49408);           // [192]
    float* bt1 = bt0 + 192;                       // [192]

    const int tid = threadIdx.x;
    const long rowbase = (long)blockIdx.x * MB;

    float* out0 = out;                                      // h1      [T*B][64]
    float* out1 = out + (long)T_SEQ * B_BATCH * H_DIM;      // h0[-1]  [128][64]
    float* out2 = out1 + B_BATCH * H_DIM;                   // c0[-1]
    float* out3 = out2 + B_BATCH * H_DIM;                   // h1[-1]
    float* out4 = out3 + B_BATCH * H_DIM;                   // c1[-1]

    // stage combined bias + theta for gates 1..3 (flat row in (4,64) = 64 + gc)
    if (tid < 192) {
        bt0[tid] = b0[64 + tid] + th0[64 + tid];
        bt1[tid] = b1[64 + tid] + th1[64 + tid];
    }

    const int lane = tid & 63;
    const int wave = tid >> 6;
    const int ln   = lane & 15;   // MFMA m/n lane index
    const int quad = lane >> 4;   // MFMA k-group / row-group
    const int cw   = wave * 48;   // this wave's N-column base (192 cols / 4 waves)

    // packed-B per-wave bases: every load below is base + lane*8 (coalesced 1KB)
    const short* wb0 = wsp + wave * 73728 + lane * 8;          // W0 fragments
    const short* wb1 = wsp + W1P + wave * 9216 + lane * 8;     // W1 fragments

    // staging geometry: each thread owns 16 contiguous cols of one row per K=64 chunk
    const int sr = tid >> 2;            // row 0..63
    const int sc = (tid & 3) << 4;      // col base 0,16,32,48
    const float* xrow = x + (rowbase + sr) * 512 + sc;
    const int sao = sr * A1S + sc;

    // ------- GEMM1: z0[64][192] = x[64][512] . W0g^T, K chunks of 64, async-staged
    f32x4 acc[4][3];
    #pragma unroll
    for (int mt = 0; mt < 4; ++mt)
        #pragma unroll
        for (int nt = 0; nt < 3; ++nt)
            acc[mt][nt] = (f32x4){0.f, 0.f, 0.f, 0.f};

    {   // prologue: stage chunk 0
        float4 f[4];
        #pragma unroll
        for (int u = 0; u < 4; ++u) f[u] = *(const float4*)(xrow + u * 4);
        split16(f, ah, am, al, sao);
    }
    __syncthreads();

    for (int kc = 0; kc < 512; kc += 64) {
        // async-stage: issue next chunk's global loads BEFORE compute;
        // latency hides under the MFMA phase; split+write after the barrier.
        float4 nf[4];
        const bool more = (kc + 64) < 512;
        if (more) {
            #pragma unroll
            for (int u = 0; u < 4; ++u)
                nf[u] = *(const float4*)(xrow + kc + 64 + u * 4);
        }
        const short* wc = wb0 + (kc >> 6) * 9216;
        #pragma unroll
        for (int k0 = 0; k0 < 64; k0 += 32) {
            int ka = k0 + quad * 8;
            const short* wk = wc + (k0 >> 5) * 4608;
            bf16x8 Ah[4], Am[4], Al[4];
            #pragma unroll
            for (int mt = 0; mt < 4; ++mt) {
                int ao = (mt * 16 + ln) * A1S + ka;
                Ah[mt] = *(const bf16x8*)(ah + ao);
                Am[mt] = *(const bf16x8*)(am + ao);
                Al[mt] = *(const bf16x8*)(al + ao);
            }
            #pragma unroll
            for (int nt = 0; nt < 3; ++nt) {
                const short* wt = wk + nt * 1536;
                bf16x8 Bh = *(const bf16x8*)(wt);
                bf16x8 Bm = *(const bf16x8*)(wt + 512);
                bf16x8 Bl = *(const bf16x8*)(wt + 1024);
                #pragma unroll
                for (int mt = 0; mt < 4; ++mt)
                    acc[mt][nt] = mfma6(Ah[mt], Am[mt], Al[mt], Bh, Bm, Bl, acc[mt][nt]);
            }
        }
        __syncthreads();   // plane reads done before overwrite / zs epilogue
        if (more) {
            split16(nf, ah, am, al, sao);
            __syncthreads();
        }
    }

    // epilogue: D[m][n]: col = lane&15, row = quad*4 + reg  [measured m89/m91]
    #pragma unroll
    for (int mt = 0; mt < 4; ++mt)
        #pragma unroll
        for (int nt = 0; nt < 3; ++nt)
            #pragma unroll
            for (int i = 0; i < 4; ++i) {
                int row = mt * 16 + quad * 4 + i;
                int col = cw + nt * 16 + ln;
                zs[row * ZS_STRIDE + col] = acc[mt][nt][i];
            }
    __syncthreads();

    // ------- cumprod(cos(z + b + th)) layer 0 (wave-uniform: wave 3 idles)
    if (tid < 192) {
        int gi = tid >> 6;
        int r  = tid & 63;
        float* zrow = zs + r * ZS_STRIDE + gi * 64;
        const float* btg = bt0 + gi * 64;
        float p = 1.0f;
        for (int n = 0; n < 64; ++n) {
            p *= fast_cos(zrow[n] + btg[n]);
            zrow[n] = p;
        }
    }
    __syncthreads();

    // ------- gates + two-pass LayerNorm layer 0 -> registers -> split A2 planes
    {
        int r = tid >> 2;            // row 0..63
        int j = tid & 3;             // 16-element chunk
        long tbrow = rowbase + r;
        bool lastt = (tbrow >= LASTROW);
        int bidx = (int)(tbrow - LASTROW);
        const float* zr = zs + r * ZS_STRIDE;
        float h[16];
        float s = 0.f;
        #pragma unroll
        for (int i = 0; i < 16; ++i) {
            int n = j * 16 + i;
            float q1 = zr[n];            // gate 1 (input)
            float q2 = zr[64 + n];       // gate 2 (update)
            float q3 = zr[128 + n];      // gate 3 (output)
            float ig = fast_sigmoid(q1);
            float gg = fast_tanh_pos(fast_sigmoid(q2));
            float og = fast_sigmoid(q3);
            float c  = ig * gg;
            float hv = og * fast_tanh_pos(c);
            h[i] = hv;
            s += hv;
            if (lastt) out2[bidx * 64 + n] = c;
        }
        s += __shfl_xor(s, 1);  s += __shfl_xor(s, 2);
        float mu = s * (1.0f / 64.0f);
        float s2 = 0.f;
        #pragma unroll
        for (int i = 0; i < 16; ++i) {           // two-pass: matches mean((h-mu)^2)
            float d = h[i] - mu;
            s2 += d * d;
        }
        s2 += __shfl_xor(s2, 1); s2 += __shfl_xor(s2, 2);
        float var = s2 * (1.0f / 64.0f);
        float rs  = rsqrtf(var + 1e-5f);
        float hl[16];
        #pragma unroll
        for (int i = 0; i < 16; ++i) {
            int n = j * 16 + i;
            hl[i] = (h[i] - mu) * rs * g0[n] + be0[n];
            if (lastt) out1[bidx * 64 + n] = hl[i];
        }
        __syncthreads();   // all zs reads done before A2 planes overwrite the region

        // split ONCE into layer-2 A planes
        int ab = r * A2S + j * 16;
        uint4 Ph, Pm, Pl;
        tsplit2(hl[0], hl[1], Ph.x, Pm.x, Pl.x);
        tsplit2(hl[2], hl[3], Ph.y, Pm.y, Pl.y);
        tsplit2(hl[4], hl[5], Ph.z, Pm.z, Pl.z);
        tsplit2(hl[6], hl[7], Ph.w, Pm.w, Pl.w);
        *(uint4*)(a2h + ab) = Ph;
        *(uint4*)(a2m + ab) = Pm;
        *(uint4*)(a2l + ab) = Pl;
        tsplit2(hl[8],  hl[9],  Ph.x, Pm.x, Pl.x);
        tsplit2(hl[10], hl[11], Ph.y, Pm.y, Pl.y);
        tsplit2(hl[12], hl[13], Ph.z, Pm.z, Pl.z);
        tsplit2(hl[14], hl[15], Ph.w, Pm.w, Pl.w);
        *(uint4*)(a2h + ab + 8) = Ph;
        *(uint4*)(a2m + ab + 8) = Pm;
        *(uint4*)(a2l + ab + 8) = Pl;
    }
    __syncthreads();

    // ------- GEMM2: z1[64][192] = h0[64][64] . W1g^T, pre-split A2 planes, K=64
    f32x4 acc2[4][3];
    #pragma unroll
    for (int mt = 0; mt < 4; ++mt)
        #pragma unroll
        for (int nt = 0; nt < 3; ++nt)
            acc2[mt][nt] = (f32x4){0.f, 0.f, 0.f, 0.f};
    #pragma unroll
    for (int k0 = 0; k0 < 64; k0 += 32) {
        int ka = k0 + quad * 8;
        const short* wk = wb1 + (k0 >> 5) * 4608;
        bf16x8 Ah[4], Am[4], Al[4];
        #pragma unroll
        for (int mt = 0; mt < 4; ++mt) {
            int ao = (mt * 16 + ln) * A2S + ka;
            Ah[mt] = *(const bf16x8*)(a2h + ao);
            Am[mt] = *(const bf16x8*)(a2m + ao);
            Al[mt] = *(const bf16x8*)(a2l + ao);
        }
        #pragma unroll
        for (int nt = 0; nt < 3; ++nt) {
            const short* wt = wk + nt * 1536;
            bf16x8 Bh = *(const bf16x8*)(wt);
            bf16x8 Bm = *(const bf16x8*)(wt + 512);
            bf16x8 Bl = *(const bf16x8*)(wt + 1024);
            #pragma unroll
            for (int mt = 0; mt < 4; ++mt)
                acc2[mt][nt] = mfma6(Ah[mt], Am[mt], Al[mt], Bh, Bm, Bl, acc2[mt][nt]);
        }
    }
    __syncthreads();   // A2 plane reads done before zs epilogue overwrites region
    #pragma unroll
    for (int mt = 0; mt < 4; ++mt)
        #pragma unroll
        for (int nt = 0; nt < 3; ++nt)
            #pragma unroll
            for (int i = 0; i < 4; ++i) {
                int row = mt * 16 + quad * 4 + i;
                int col = cw + nt * 16 + ln;
                zs[row * ZS_STRIDE + col] = acc2[mt][nt][i];
            }
    __syncthreads();

    // ------- cumprod layer 1
    if (tid < 192) {
        int gi = tid >> 6;
        int r  = tid & 63;
        float* zrow = zs + r * ZS_STRIDE + gi * 64;
        const float* btg = bt1 + gi * 64;
        float p = 1.0f;
        for (int n = 0; n < 64; ++n) {
            p *= fast_cos(zrow[n] + btg[n]);
            zrow[n] = p;
        }
    }
    __syncthreads();

    // ------- gates + two-pass LayerNorm layer 1 -> out0 directly (+ out3/out4)
    {
        int r = tid >> 2;
        int j = tid & 3;
        long tbrow = rowbase + r;
        bool lastt = (tbrow >= LASTROW);
        int bidx = (int)(tbrow - LASTROW);
        const float* zr = zs + r * ZS_STRIDE;
        float h[16];
        float s = 0.f;
        #pragma unroll
        for (int i = 0; i < 16; ++i) {
            int n = j * 16 + i;
            float q1 = zr[n];
            float q2 = zr[64 + n];
            float q3 = zr[128 + n];
            float ig = fast_sigmoid(q1);
            float gg = fast_tanh_pos(fast_sigmoid(q2));
            float og = fast_sigmoid(q3);
            float c  = ig * gg;
            float hv = og * fast_tanh_pos(c);
            h[i] = hv;
            s += hv;
            if (lastt) out4[bidx * 64 + n] = c;
        }
        s += __shfl_xor(s, 1);  s += __shfl_xor(s, 2);
        float mu = s * (1.0f / 64.0f);
        float s2 = 0.f;
        #pragma unroll
        for (int i = 0; i < 16; ++i) {
            float d = h[i] - mu;
            s2 += d * d;
        }
        s2 += __shfl_xor(s2, 1); s2 += __shfl_xor(s2, 2);
        float var = s2 * (1.0f / 64.0f);
        float rs  = rsqrtf(var + 1e-5f);
        float o4[16];
        #pragma unroll
        for (int i = 0; i < 16; ++i)
            o4[i] = (h[i] - mu) * rs * g1[j * 16 + i] + be1[j * 16 + i];
        float* dst = out0 + tbrow * 64 + j * 16;
        #pragma unroll
        for (int i4 = 0; i4 < 4; ++i4)
            *(float4*)(dst + i4 * 4) = *(float4*)(o4 + i4 * 4);
        if (lastt) {
            float* dst3 = out3 + (long)bidx * 64 + j * 16;
            #pragma unroll
            for (int i4 = 0; i4 < 4; ++i4)
                *(float4*)(dst3 + i4 * 4) = *(float4*)(o4 + i4 * 4);
        }
    }
}

extern "C" void kernel_launch(void* const* d_in, const int* in_sizes, int n_in,
                              void* d_out, int out_size, void* d_ws, size_t ws_size,
                              hipStream_t stream) {
    const float* x   = (const float*)d_in[0];
    const float* W0  = (const float*)d_in[1];
    const float* b0  = (const float*)d_in[2];
    const float* th0 = (const float*)d_in[3];
    const float* g0  = (const float*)d_in[4];
    const float* be0 = (const float*)d_in[5];
    const float* W1  = (const float*)d_in[6];
    const float* b1  = (const float*)d_in[7];
    const float* th1 = (const float*)d_in[8];
    const float* g1  = (const float*)d_in[9];
    const float* be1 = (const float*)d_in[10];
    short* wsp = (short*)d_ws;     // needs 663552 B

    presplit_w<<<dim3(432), dim3(256), 0, stream>>>(W0, W1, wsp);
    qlstm_fused<<<dim3(1024), dim3(256), 0, stream>>>(
        x, b0, th0, g0, be0, b1, th1, g1, be1, wsp, (float*)d_out);
}